// Round 8
// baseline (237.042 us; speedup 1.0000x reference)
//
#include <hip/hip_runtime.h>
#include <cstdint>

// Problem constants: B=8, N=1024, C=256, heads=4, hd=64
typedef _Float16 h16;
typedef __attribute__((ext_vector_type(8))) _Float16 f16x8;
typedef __attribute__((ext_vector_type(4))) _Float16 f16x4;
typedef __attribute__((ext_vector_type(4))) float f32x4;

#define L2E 1.44269504f           // log2(e)
#define QSCALE (0.125f * L2E)     // hd^-0.5 * log2(e)

// ---------------------------------------------------------------------------
// 1) cast x,qkv_w,proj_w -> fp16; fused xm row-mean
__global__ void k_cast(const float* __restrict__ x, const float* __restrict__ qw,
                       const float* __restrict__ pw, h16* __restrict__ xh,
                       h16* __restrict__ qwh, h16* __restrict__ pwh,
                       float* __restrict__ xm) {
  int bid = blockIdx.x, tid = threadIdx.x;
  if (bid < 2048) {  // x part
    int i4 = bid * 256 + tid;
    float4 v = ((const float4*)x)[i4];
    f16x4 o = {(h16)v.x, (h16)v.y, (h16)v.z, (h16)v.w};
    ((f16x4*)xh)[i4] = o;
    float s = v.x + v.y + v.z + v.w;
#pragma unroll
    for (int off = 32; off; off >>= 1) s += __shfl_xor(s, off);
    if ((tid & 63) == 0) xm[i4 >> 6] = s * (1.0f / 256.0f);
  } else {
    int i4 = (bid - 2048) * 256 + tid;
    if (i4 < 49152) {
      float4 v = ((const float4*)qw)[i4];
      f16x4 o = {(h16)v.x, (h16)v.y, (h16)v.z, (h16)v.w};
      ((f16x4*)qwh)[i4] = o;
    } else {
      int j = i4 - 49152;
      float4 v = ((const float4*)pw)[j];
      f16x4 o = {(h16)v.x, (h16)v.y, (h16)v.z, (h16)v.w};
      ((f16x4*)pwh)[j] = o;
    }
  }
}

// ---------------------------------------------------------------------------
// 2) amap[b,n] = sigmoid(conv3x3(xm_grid, mean_k(kernels)))  (zero pad)
__global__ void k_amap(const float* __restrict__ xm,
                       const float* __restrict__ kern,
                       float* __restrict__ amap) {
  int idx = blockIdx.x * 256 + threadIdx.x;  // 8192
  int b = idx >> 10, n = idx & 1023;
  int y = n >> 5, xq = n & 31;
  float km[9];
#pragma unroll
  for (int i = 0; i < 9; ++i)
    km[i] = 0.25f * (kern[i] + kern[9 + i] + kern[18 + i] + kern[27 + i]);
  float acc = 0.f;
#pragma unroll
  for (int dy = 0; dy < 3; ++dy) {
#pragma unroll
    for (int dx = 0; dx < 3; ++dx) {
      int yy = y + dy - 1, xx = xq + dx - 1;
      if (yy >= 0 && yy < 32 && xx >= 0 && xx < 32)
        acc += km[dy * 3 + dx] * xm[(b << 10) + (yy << 5) + xx];
    }
  }
  amap[idx] = 1.0f / (1.0f + __expf(-acc));
}

// ---------------------------------------------------------------------------
// 3) QKV GEMM v2: 64x64 tiles, 4 waves (2x2), 256 thr -> high occupancy.
//    Q/K -> [b,h,n,64], V transposed -> [b,h,64,n]
__global__ __launch_bounds__(256, 4) void k_qkv(
    const h16* __restrict__ xh, const h16* __restrict__ qwh,
    const float* __restrict__ bias, h16* __restrict__ Qh,
    h16* __restrict__ Kh, h16* __restrict__ Vt) {
  const int tid = threadIdx.x;
  const int wave = tid >> 6, lane = tid & 63, g = lane >> 4, li = lane & 15;
  const int wr = wave >> 1, wc = wave & 1;
  const int r0 = blockIdx.x * 64 + wr * 32;   // 0..8191
  const int c0 = blockIdx.y * 64 + wc * 32;   // 0..767
  f32x4 acc[2][2];
#pragma unroll
  for (int mr = 0; mr < 2; ++mr)
#pragma unroll
    for (int nc = 0; nc < 2; ++nc) acc[mr][nc] = {0.f, 0.f, 0.f, 0.f};
  for (int ks = 0; ks < 8; ++ks) {
    int k0 = ks * 32 + g * 8;
    f16x8 a[2], bf[2];
#pragma unroll
    for (int mr = 0; mr < 2; ++mr)
      a[mr] = *(const f16x8*)(xh + (size_t)(r0 + mr * 16 + li) * 256 + k0);
#pragma unroll
    for (int nc = 0; nc < 2; ++nc)
      bf[nc] = *(const f16x8*)(qwh + (size_t)(c0 + nc * 16 + li) * 256 + k0);
#pragma unroll
    for (int mr = 0; mr < 2; ++mr)
#pragma unroll
      for (int nc = 0; nc < 2; ++nc)
        acc[mr][nc] = __builtin_amdgcn_mfma_f32_16x16x32_f16(a[mr], bf[nc],
                                                             acc[mr][nc], 0, 0, 0);
  }
  const int which = blockIdx.y >> 2;   // 0=Q 1=K 2=V
  const int hh = blockIdx.y & 3;       // head
  const int bq = r0 >> 10;
  const size_t base = ((size_t)(bq * 4 + hh)) << 16;
  if (which == 2) {  // V transposed: f16x4 runs along n
#pragma unroll
    for (int nc = 0; nc < 2; ++nc) {
      int d = (wc * 32) + nc * 16 + li;
      float bv = bias[c0 + nc * 16 + li];
#pragma unroll
      for (int mr = 0; mr < 2; ++mr) {
        int n0 = (r0 & 1023) + mr * 16 + g * 4;
        f16x4 pk = {(h16)(acc[mr][nc][0] + bv), (h16)(acc[mr][nc][1] + bv),
                    (h16)(acc[mr][nc][2] + bv), (h16)(acc[mr][nc][3] + bv)};
        *(f16x4*)(Vt + base + (size_t)d * 1024 + n0) = pk;
      }
    }
  } else {
    h16* dst = (which == 0) ? Qh : Kh;
#pragma unroll
    for (int nc = 0; nc < 2; ++nc) {
      int d = (wc * 32) + nc * 16 + li;
      float bv = bias[c0 + nc * 16 + li];
#pragma unroll
      for (int mr = 0; mr < 2; ++mr) {
#pragma unroll
        for (int r = 0; r < 4; ++r) {
          int n = (r0 & 1023) + mr * 16 + g * 4 + r;
          dst[base + (size_t)n * 64 + d] = (h16)(acc[mr][nc][r] + bv);
        }
      }
    }
  }
}

// ---------------------------------------------------------------------------
// 4) Kmax[bh] = max_n ||K[bh,n,:]||
__global__ void k_knorm(const h16* __restrict__ Kh, float* __restrict__ Kmaxb) {
  __shared__ float red[4];
  const int tid = threadIdx.x;
  const h16* base = Kh + ((size_t)blockIdx.x << 16);
  float mx = 0.f;
#pragma unroll
  for (int i = 0; i < 4; ++i) {
    int n = i * 256 + tid;
    float s2 = 0.f;
#pragma unroll
    for (int ks = 0; ks < 8; ++ks) {
      f16x8 v = *(const f16x8*)(base + (size_t)n * 64 + ks * 8);
#pragma unroll
      for (int e = 0; e < 8; ++e) {
        float f = (float)v[e];
        s2 += f * f;
      }
    }
    mx = fmaxf(mx, s2);
  }
#pragma unroll
  for (int off = 32; off; off >>= 1) mx = fmaxf(mx, __shfl_xor(mx, off));
  if ((tid & 63) == 0) red[tid >> 6] = mx;
  __syncthreads();
  if (tid == 0) {
    mx = fmaxf(fmaxf(red[0], red[1]), fmaxf(red[2], red[3]));
    Kmaxb[blockIdx.x] = sqrtf(mx);
  }
}

// ---------------------------------------------------------------------------
// 5) k_fattn v3: O-path only, single pass, NO in-loop barriers.
//    p' = 2^(sigma - CL) <= 2^10 (boost folded into shift); O = sum(p' v)/l'.
//    Stores E2 = CL + log2(l') per row for k_aw.
//    block = (b, 16-row tile), 8 waves = (head, j-half), free drift.
__global__ __launch_bounds__(512, 4) void k_fattn(
    const h16* __restrict__ Qh, const h16* __restrict__ Kh,
    const h16* __restrict__ Vt, const float* __restrict__ amap,
    const float* __restrict__ Kmaxb, float* __restrict__ E2b,
    h16* __restrict__ OHh) {
  __shared__ float am_s[1024];
  __shared__ float Lsh[4][2][16];
  __shared__ float Osh[4][16][64];

  const int tid = threadIdx.x;
  const int wave = tid >> 6, lane = tid & 63, g = lane >> 4, li = lane & 15;
  const int h = wave >> 1, jh = wave & 1;
  const int b = blockIdx.x & 7, rt = blockIdx.x >> 3;
  const int r0 = rt * 16;
  const int bh = b * 4 + h;
  const size_t base = ((size_t)bh) << 16;

  am_s[tid] = amap[(b << 10) + tid];
  am_s[tid + 512] = amap[(b << 10) + 512 + tid];
  __syncthreads();

  // Q fragment (B-operand): lane(g,li) holds q-row r0+li, d = ks*32+g*8..+7
  f16x8 qf[2];
#pragma unroll
  for (int ks = 0; ks < 2; ++ks)
    qf[ks] = *(const f16x8*)(Qh + base + (size_t)(r0 + li) * 64 + ks * 32 + g * 8);

  // shift bound c = 0.125*||q||*Kmax + margin; CL = c*log2e - 10 (boost)
  float nq2 = 0.f;
#pragma unroll
  for (int ks = 0; ks < 2; ++ks)
#pragma unroll
    for (int e = 0; e < 8; ++e) {
      float f = (float)qf[ks][e];
      nq2 += f * f;
    }
  nq2 += __shfl_xor(nq2, 16);
  nq2 += __shfl_xor(nq2, 32);
  const float c = 0.125f * sqrtf(nq2) * Kmaxb[bh] + 0.11f;
  const float CL = c * L2E - 10.0f;
  const float amr2 = 0.1f * L2E * am_s[r0 + li];
  const int prow = ((li >> 2) << 3) + (li & 3);  // permuted K-row base

  float lpart = 0.f;
  f32x4 o[4];
#pragma unroll
  for (int nd = 0; nd < 4; ++nd) o[nd] = {0.f, 0.f, 0.f, 0.f};

  for (int jj = 0; jj < 8; ++jj) {
    const int j0 = jh * 512 + jj * 64;
    f16x8 bf[2];
#pragma unroll
    for (int u = 0; u < 2; ++u) {
      f32x4 s[2], am4[2];
#pragma unroll
      for (int ab = 0; ab < 2; ++ab) {
        const int rK = j0 + u * 32 + ab * 4 + prow;
        f16x8 k0 = *(const f16x8*)(Kh + base + (size_t)rK * 64 + g * 8);
        f16x8 k1 = *(const f16x8*)(Kh + base + (size_t)rK * 64 + 32 + g * 8);
        f32x4 a = {0.f, 0.f, 0.f, 0.f};
        a = __builtin_amdgcn_mfma_f32_16x16x32_f16(k0, qf[0], a, 0, 0, 0);
        a = __builtin_amdgcn_mfma_f32_16x16x32_f16(k1, qf[1], a, 0, 0, 0);
        s[ab] = a;
        am4[ab] = *(const f32x4*)&am_s[j0 + u * 32 + g * 8 + ab * 4];
      }
      f16x8 pk;
#pragma unroll
      for (int ab = 0; ab < 2; ++ab)
#pragma unroll
        for (int r = 0; r < 4; ++r) {
          float p = exp2f(fmaf(s[ab][r], QSCALE, fmaf(amr2, am4[ab][r], -CL)));
          lpart += p;
          pk[ab * 4 + r] = (h16)p;
        }
      bf[u] = pk;
    }
    // PV: o += V * p'  (register-only, no LDS)
#pragma unroll
    for (int nd = 0; nd < 4; ++nd) {
      const h16* vb = Vt + base + (size_t)(nd * 16 + li) * 1024 + j0 + g * 8;
      f16x8 v0 = *(const f16x8*)(vb);
      f16x8 v1 = *(const f16x8*)(vb + 32);
      o[nd] = __builtin_amdgcn_mfma_f32_16x16x32_f16(v0, bf[0], o[nd], 0, 0, 0);
      o[nd] = __builtin_amdgcn_mfma_f32_16x16x32_f16(v1, bf[1], o[nd], 0, 0, 0);
    }
  }

  // epilogue: l' across jh -> rinv, E2; O combine across jh
  lpart += __shfl_xor(lpart, 16);
  lpart += __shfl_xor(lpart, 32);
  if (lane < 16) Lsh[h][jh][li] = lpart;
  __syncthreads();
  const float l = Lsh[h][0][li] + Lsh[h][1][li];
  const float rinv = 1.0f / l;
  if (jh == 0 && lane < 16)
    E2b[((size_t)bh << 10) + r0 + li] = CL + __log2f(l);
  if (jh == 1) {
#pragma unroll
    for (int nd = 0; nd < 4; ++nd)
      *(f32x4*)&Osh[h][li][nd * 16 + g * 4] = o[nd];
  }
  __syncthreads();
  if (jh == 0) {
#pragma unroll
    for (int nd = 0; nd < 4; ++nd) {
      f32x4 p = *(const f32x4*)&Osh[h][li][nd * 16 + g * 4];
      f16x4 pk = {(h16)((o[nd][0] + p[0]) * rinv), (h16)((o[nd][1] + p[1]) * rinv),
                  (h16)((o[nd][2] + p[2]) * rinv), (h16)((o[nd][3] + p[3]) * rinv)};
      *(f16x4*)(OHh + (size_t)((b << 10) + r0 + li) * 256 + h * 64 + nd * 16 +
                g * 4) = pk;
    }
  }
}

// ---------------------------------------------------------------------------
// 6) k_aw: AW[b,i,j] = 0.25 * sum_h 2^(sigma_h - E2_h).  Recompute QK^T.
//    block = (b, 16-row tile, 256-col quarter), 4 waves = heads. ONE barrier.
__global__ __launch_bounds__(256, 4) void k_aw(
    const h16* __restrict__ Qh, const h16* __restrict__ Kh,
    const float* __restrict__ amap, const float* __restrict__ E2b,
    float* __restrict__ AW) {
  __shared__ float am_c[256];
  __shared__ __align__(16) unsigned char Pst[4][8192];  // [h][16r x 256c h16, swz]

  const int tid = threadIdx.x;
  const int h = tid >> 6, lane = tid & 63, g = lane >> 4, li = lane & 15;
  const int bid = blockIdx.x;
  const int jq = bid & 3, it = (bid >> 2) & 63, b = bid >> 8;
  const int r0 = it * 16, jbase = jq * 256;
  const int bh = b * 4 + h;
  const size_t base = ((size_t)bh) << 16;

  am_c[tid] = amap[(b << 10) + jbase + tid];
  __syncthreads();

  f16x8 qf[2];
#pragma unroll
  for (int ks = 0; ks < 2; ++ks)
    qf[ks] = *(const f16x8*)(Qh + base + (size_t)(r0 + li) * 64 + ks * 32 + g * 8);

  const float E2 = E2b[((size_t)bh << 10) + r0 + li];
  const float amr2 = 0.1f * L2E * amap[(b << 10) + r0 + li];
  const int prow = ((li >> 2) << 3) + (li & 3);
  const int swz = (li & 7) << 4;

  for (int jj = 0; jj < 4; ++jj) {
    const int j0 = jbase + jj * 64;  // global col
    const int j0l = jj * 64;         // local col
#pragma unroll
    for (int u = 0; u < 2; ++u) {
      f32x4 s[2], am4[2];
#pragma unroll
      for (int ab = 0; ab < 2; ++ab) {
        const int rK = j0 + u * 32 + ab * 4 + prow;
        f16x8 k0 = *(const f16x8*)(Kh + base + (size_t)rK * 64 + g * 8);
        f16x8 k1 = *(const f16x8*)(Kh + base + (size_t)rK * 64 + 32 + g * 8);
        f32x4 a = {0.f, 0.f, 0.f, 0.f};
        a = __builtin_amdgcn_mfma_f32_16x16x32_f16(k0, qf[0], a, 0, 0, 0);
        a = __builtin_amdgcn_mfma_f32_16x16x32_f16(k1, qf[1], a, 0, 0, 0);
        s[ab] = a;
        am4[ab] = *(const f32x4*)&am_c[j0l + u * 32 + g * 8 + ab * 4];
      }
      f16x8 pk;
#pragma unroll
      for (int ab = 0; ab < 2; ++ab)
#pragma unroll
        for (int r = 0; r < 4; ++r)
          pk[ab * 4 + r] =
              (h16)exp2f(fmaf(s[ab][r], QSCALE, fmaf(amr2, am4[ab][r], -E2)));
      const int col = j0l + u * 32 + g * 8;
      *(f16x8*)(&Pst[h][((li << 9) + col * 2) ^ swz]) = pk;
    }
  }
  __syncthreads();
  // head-mean reduce: thread -> (row ar, 16 cols at cb)
  const int ar = tid >> 4, cb = (tid & 15) << 4;
  const int aswz = (ar & 7) << 4;
  float sum[16];
#pragma unroll
  for (int e = 0; e < 16; ++e) sum[e] = 0.f;
#pragma unroll
  for (int h2 = 0; h2 < 4; ++h2) {
    f16x8 v0 = *(const f16x8*)(&Pst[h2][((ar << 9) + cb * 2) ^ aswz]);
    f16x8 v1 = *(const f16x8*)(&Pst[h2][((ar << 9) + cb * 2 + 16) ^ aswz]);
#pragma unroll
    for (int e = 0; e < 8; ++e) {
      sum[e] += (float)v0[e];
      sum[8 + e] += (float)v1[e];
    }
  }
  float* dst = AW + ((size_t)b << 20) + (size_t)(r0 + ar) * 1024 + jbase + cb;
#pragma unroll
  for (int q = 0; q < 4; ++q) {
    float4 ov = {0.25f * sum[q * 4], 0.25f * sum[q * 4 + 1],
                 0.25f * sum[q * 4 + 2], 0.25f * sum[q * 4 + 3]};
    *(float4*)(dst + q * 4) = ov;
  }
}

// ---------------------------------------------------------------------------
// 7) proj GEMM v2: 16x64 tiles, 4 waves (16 cols each), grid 2048.
__global__ __launch_bounds__(256, 4) void k_proj(
    const h16* __restrict__ OHh, const h16* __restrict__ pwh,
    const float* __restrict__ bias, float* __restrict__ out) {
  const int tid = threadIdx.x;
  const int wave = tid >> 6, lane = tid & 63, g = lane >> 4, li = lane & 15;
  const int tr = blockIdx.x >> 2, tcq = blockIdx.x & 3;
  const int r0 = tr * 16, c0 = tcq * 64 + wave * 16;
  f32x4 acc = {0.f, 0.f, 0.f, 0.f};
  for (int ks = 0; ks < 8; ++ks) {
    int k0 = ks * 32 + g * 8;
    f16x8 a = *(const f16x8*)(OHh + (size_t)(r0 + li) * 256 + k0);
    f16x8 bf = *(const f16x8*)(pwh + (size_t)(c0 + li) * 256 + k0);
    acc = __builtin_amdgcn_mfma_f32_16x16x32_f16(a, bf, acc, 0, 0, 0);
  }
  const int cc = c0 + li;
  const float bv = bias[cc];
#pragma unroll
  for (int r = 0; r < 4; ++r) {
    int m = r0 + g * 4 + r;
    out[(size_t)m * 256 + cc] = acc[r] + bv;
  }
}

// ---------------------------------------------------------------------------
// 8) reg loss
__global__ void k_reg(const float* __restrict__ kern, float* __restrict__ out) {
  const float Cst[36] = {
      -1.f, -1.f, -1.f, 2.f, 2.f, 2.f, -1.f, -1.f, -1.f,
      -0.11111111f, 0.f, -0.11111111f, 0.f, 4.f, 0.f,
      -0.11111111f, 0.f, -0.11111111f,
      0.f, -1.f, 0.f, -1.f, 4.f, -1.f, 0.f, -1.f, 0.f,
      -1.f, 0.f, -1.f, 0.f, 4.f, 0.f, -1.f, 0.f, -1.f};
  int t = threadIdx.x;
  float v = 0.f;
  if (t < 36) {
    float kv = kern[t];
    float d = kv - Cst[t];
    v = d * d * (1.0f / 9.0f) + 0.01f * fabsf(kv);
  }
#pragma unroll
  for (int off = 32; off; off >>= 1) v += __shfl_xor(v, off);
  if (t == 0) out[0] = v;
}

// ---------------------------------------------------------------------------
extern "C" void kernel_launch(void* const* d_in, const int* in_sizes, int n_in,
                              void* d_out, int out_size, void* d_ws,
                              size_t ws_size, hipStream_t stream) {
  const float* x = (const float*)d_in[0];
  const float* qkv_w = (const float*)d_in[1];
  const float* qkv_b = (const float*)d_in[2];
  const float* proj_w = (const float*)d_in[3];
  const float* proj_b = (const float*)d_in[4];
  const float* kern = (const float*)d_in[5];

  float* out = (float*)d_out;   // [8,1024,256]
  float* aw = out + 2097152;    // [8,1024,1024]
  float* rl = out + 10485760;   // scalar

  float* xm = (float*)d_ws;        // 8192 f32
  float* amap = xm + 8192;         // 8192 f32
  float* E2b = amap + 8192;        // 32768 f32 [bh,n]
  float* Kmaxb = E2b + 32768;      // 32 f32 (+pad)
  h16* xh = (h16*)(Kmaxb + 64);    // 2097152
  h16* qwh = xh + 2097152;         // 196608
  h16* pwh = qwh + 196608;         // 65536
  h16* Qh = pwh + 65536;           // 2097152  [b,h,n,64]
  h16* Kh = Qh + 2097152;          // 2097152  [b,h,n,64]
  h16* Vt = Kh + 2097152;          // 2097152  [b,h,64,1024]
  h16* OHh = Vt + 2097152;         // 2097152  [b,n,256]

  k_cast<<<2304, 256, 0, stream>>>(x, qkv_w, proj_w, xh, qwh, pwh, xm);
  k_amap<<<32, 256, 0, stream>>>(xm, kern, amap);
  k_qkv<<<dim3(128, 12), 256, 0, stream>>>(xh, qwh, qkv_b, Qh, Kh, Vt);
  k_knorm<<<32, 256, 0, stream>>>(Kh, Kmaxb);
  k_fattn<<<512, 512, 0, stream>>>(Qh, Kh, Vt, amap, Kmaxb, E2b, OHh);
  k_aw<<<2048, 256, 0, stream>>>(Qh, Kh, amap, E2b, aw);
  k_proj<<<2048, 256, 0, stream>>>(OHh, pwh, proj_b, out);
  k_reg<<<1, 64, 0, stream>>>(kern, rl);
}